// Round 2
// baseline (160.953 us; speedup 1.0000x reference)
//
#include <hip/hip_runtime.h>
#include <math.h>

typedef float f4 __attribute__((ext_vector_type(4)));

// ---------------------------------------------------------------------------
// Fully fused kernel.
//
// Per-block LDS param table p[64]:
//   p[0..5]          : interior knot boundaries kk1..kk6 (interval search)
//   p[8+i*8 + 0..3]  : cubic coeffs c0..c3 for interval i (k = 3+i), in u = xq - tk
//   p[8+i*8 + 4]     : tk (left knot of interval i)
//
// Thread 0 of every block computes the params (~600 serial ops; weights are
// L2-hot after the first blocks). All threads prefetch their 8 float4s of x
// BEFORE the params barrier so HBM stays busy during the serial phase.
// ---------------------------------------------------------------------------
__device__ __forceinline__ float eval_one(float xv, const float* __restrict__ p,
                                          float k1, float k2, float k3,
                                          float k4, float k5, float k6)
{
    // xq = clip(x / sqrt(3), 0, 0.9999)
    float xq = fminf(fmaxf(xv * 0.57735026918962576f, 0.0f), 0.9999f);
    // digitize(side-left) - 1 - 3: count of interior knots <= xq
    int i = (xq >= k1) + (xq >= k2) + (xq >= k3) + (xq >= k4) + (xq >= k5) + (xq >= k6);
    const f4 cf = *reinterpret_cast<const f4*>(p + 8 + i * 8);
    const float u = xq - p[8 + i * 8 + 4];
    return fmaf(fmaf(fmaf(cf.w, u, cf.z), u, cf.y), u, cf.x);
}

__global__ __launch_bounds__(256) void nsf_fused_kernel(
    const float* __restrict__ x,
    const float* __restrict__ a,
    const float* __restrict__ W1, const float* __restrict__ b1,
    const float* __restrict__ W2, const float* __restrict__ b2,
    const float* __restrict__ Ww, const float* __restrict__ bw,
    const float* __restrict__ Wk, const float* __restrict__ bk,
    float* __restrict__ out, int n)
{
    __shared__ __align__(16) float p[64];

    const int n4 = n >> 2;
    const int gid = blockIdx.x * blockDim.x + threadIdx.x;
    const int stride = gridDim.x * blockDim.x;
    const f4* __restrict__ x4 = reinterpret_cast<const f4*>(x);
    f4* __restrict__ o4 = reinterpret_cast<f4*>(out);

    // ---- prefetch phase: issue all loads before the barrier -------------
    f4 v[8];
#pragma unroll
    for (int it = 0; it < 8; ++it) {
        const int idx = gid + it * stride;
        if (idx < n4) v[it] = __builtin_nontemporal_load(x4 + idx);
    }

    // ---- params phase (thread 0) ----------------------------------------
    if (threadIdx.x == 0) {
        const float av = a[0];
        float n1[16], n2[16];
        for (int j = 0; j < 16; ++j) n1[j] = sinf(av * W1[j] + b1[j]);
        for (int j = 0; j < 16; ++j) {
            float s = b2[j];
            for (int i = 0; i < 16; ++i) s += n1[i] * W2[i * 16 + j];
            n2[j] = sinf(s);
        }
        float w[9];
        for (int j = 0; j < 9; ++j) {
            float s = bw[j];
            for (int i = 0; i < 16; ++i) s += n2[i] * Ww[i * 9 + j];
            w[j] = s;
        }
        float kr[7];
        for (int j = 0; j < 7; ++j) {
            float s = bk[j];
            for (int i = 0; i < 16; ++i) s += n2[i] * Wk[i * 7 + j];
            kr[j] = s;
        }

        // softmax + cumsum -> interior knots in (0,1]
        float m = kr[0];
        for (int j = 1; j < 7; ++j) m = fmaxf(m, kr[j]);
        float e[7], se = 0.f;
        for (int j = 0; j < 7; ++j) { e[j] = expf(kr[j] - m); se += e[j]; }
        const float inv = 1.f / se;

        // padded knot vector t[14] = [0,0,0, 0, kk1..kk6, kk7, 1,1,1]
        float t[14], c[10];
        t[0] = t[1] = t[2] = t[3] = 0.f;
        float cum = 0.f;
        for (int j = 0; j < 7; ++j) { cum += e[j] * inv; t[4 + j] = cum; }
        t[11] = t[12] = t[13] = 1.f;

        c[0] = 0.f;
        for (int j = 0; j < 9; ++j) c[1 + j] = w[j];

        for (int j = 0; j < 6; ++j) p[j] = t[4 + j];

        // Per-interval symbolic de Boor: d[j] as cubic polys in u = xq - t[k].
        // alpha = (xq - tlo)/(thi - tlo) = A + B*u; denominators strictly > 0
        // (every (tlo,thi) pair spans at least one interior knot gap).
        for (int i = 0; i < 7; ++i) {
            const int k = 3 + i;
            const float tk = t[k];
            float d[4][4];
            for (int j = 0; j < 4; ++j) {
                d[j][0] = c[k - 3 + j];
                d[j][1] = d[j][2] = d[j][3] = 0.f;
            }
            for (int r = 1; r <= 3; ++r) {
                for (int j = 3; j >= r; --j) {
                    const float tlo = t[k + j - 3];
                    const float thi = t[k + j + 1 - r];
                    const float B = 1.f / (thi - tlo);
                    const float A = (tk - tlo) * B;
                    float nd[4];
                    for (int nn = 0; nn < 4; ++nn) nd[nn] = d[j - 1][nn];
                    for (int nn = 0; nn < r; ++nn) {
                        const float en = d[j][nn] - d[j - 1][nn];
                        nd[nn]     += A * en;
                        nd[nn + 1] += B * en;
                    }
                    for (int nn = 0; nn < 4; ++nn) d[j][nn] = nd[nn];
                }
            }
            p[8 + i * 8 + 0] = d[3][0];
            p[8 + i * 8 + 1] = d[3][1];
            p[8 + i * 8 + 2] = d[3][2];
            p[8 + i * 8 + 3] = d[3][3];
            p[8 + i * 8 + 4] = tk;
        }
    }
    __syncthreads();

    const float k1 = p[0], k2 = p[1], k3 = p[2], k4 = p[3], k5 = p[4], k6 = p[5];

    // ---- eval + store phase ---------------------------------------------
#pragma unroll
    for (int it = 0; it < 8; ++it) {
        const int idx = gid + it * stride;
        if (idx < n4) {
            f4 r;
            r.x = eval_one(v[it].x, p, k1, k2, k3, k4, k5, k6);
            r.y = eval_one(v[it].y, p, k1, k2, k3, k4, k5, k6);
            r.z = eval_one(v[it].z, p, k1, k2, k3, k4, k5, k6);
            r.w = eval_one(v[it].w, p, k1, k2, k3, k4, k5, k6);
            __builtin_nontemporal_store(r, o4 + idx);
        }
    }

    // generic overflow guard (empty at n = 256^3 with the launch config below)
    for (int idx = gid + 8 * stride; idx < n4; idx += stride) {
        const f4 vv = x4[idx];
        f4 r;
        r.x = eval_one(vv.x, p, k1, k2, k3, k4, k5, k6);
        r.y = eval_one(vv.y, p, k1, k2, k3, k4, k5, k6);
        r.z = eval_one(vv.z, p, k1, k2, k3, k4, k5, k6);
        r.w = eval_one(vv.w, p, k1, k2, k3, k4, k5, k6);
        o4[idx] = r;
    }
    // scalar tail (n % 4 != 0 safety; empty here)
    for (int j = (n4 << 2) + gid; j < n; j += stride)
        out[j] = eval_one(x[j], p, k1, k2, k3, k4, k5, k6);
}

extern "C" void kernel_launch(void* const* d_in, const int* in_sizes, int n_in,
                              void* d_out, int out_size, void* d_ws, size_t ws_size,
                              hipStream_t stream)
{
    const float* x  = (const float*)d_in[0];
    const float* a  = (const float*)d_in[1];
    const float* W1 = (const float*)d_in[2];
    const float* b1 = (const float*)d_in[3];
    const float* W2 = (const float*)d_in[4];
    const float* b2 = (const float*)d_in[5];
    const float* Ww = (const float*)d_in[6];
    const float* bw = (const float*)d_in[7];
    const float* Wk = (const float*)d_in[8];
    const float* bk = (const float*)d_in[9];
    float* out = (float*)d_out;
    const int n = out_size;

    // 8 float4s per thread: grid = ceil(n/4 / (256*8)). n=256^3 -> 2048 blocks.
    const int n4 = n >> 2;
    int blocks = (n4 + 256 * 8 - 1) / (256 * 8);
    if (blocks < 1) blocks = 1;

    hipLaunchKernelGGL(nsf_fused_kernel, dim3(blocks), dim3(256), 0, stream,
                       x, a, W1, b1, W2, b2, Ww, bw, Wk, bk, out, n);
}

// Round 3
// 128.142 us; speedup vs baseline: 1.2561x; 1.2561x over previous
//
#include <hip/hip_runtime.h>
#include <math.h>

typedef float f4 __attribute__((ext_vector_type(4)));

// ---------------------------------------------------------------------------
// Kernel 1: scalar-conditioned MLP -> spline params -> truncated-power basis.
//
// Output ws[16]:
//   ws[0..3]   : P0 cubic coeffs (c0,c1,c2,c3) in global x (interval 0, tk=0)
//   ws[4..9]   : interior knots k1..k6
//   ws[10..15] : e1..e6, the x^3-coefficient jumps across k1..k6
//
// f(xq) = P0(xq) + sum_j e_j * max(0, xq-k_j)^3   (C^2 spline identity)
//
// One block, 64 threads. MLP layers parallelized 16-wide, per-interval
// symbolic de Boor parallelized 7-wide.
// ---------------------------------------------------------------------------
__global__ void nsf_params_kernel(const float* __restrict__ a,
                                  const float* __restrict__ W1, const float* __restrict__ b1,
                                  const float* __restrict__ W2, const float* __restrict__ b2,
                                  const float* __restrict__ Ww, const float* __restrict__ bw,
                                  const float* __restrict__ Wk, const float* __restrict__ bk,
                                  float* __restrict__ ws)
{
    __shared__ float n1[16], n2[16], wv[9], krs[7], t[14], cc[10], d3[7], p0[4];
    const int tid = threadIdx.x;

    if (tid < 16) n1[tid] = sinf(a[0] * W1[tid] + b1[tid]);
    __syncthreads();

    if (tid < 16) {
        float s = b2[tid];
        for (int i = 0; i < 16; ++i) s += n1[i] * W2[i * 16 + tid];
        n2[tid] = sinf(s);
    }
    __syncthreads();

    if (tid < 9) {
        float s = bw[tid];
        for (int i = 0; i < 16; ++i) s += n2[i] * Ww[i * 9 + tid];
        wv[tid] = s;
    }
    if (tid >= 16 && tid < 23) {
        const int j = tid - 16;
        float s = bk[j];
        for (int i = 0; i < 16; ++i) s += n2[i] * Wk[i * 7 + j];
        krs[j] = s;
    }
    __syncthreads();

    if (tid == 0) {
        // softmax + cumsum -> strictly increasing interior knots in (0,1]
        float m = krs[0];
        for (int j = 1; j < 7; ++j) m = fmaxf(m, krs[j]);
        float e[7], se = 0.f;
        for (int j = 0; j < 7; ++j) { e[j] = expf(krs[j] - m); se += e[j]; }
        const float inv = 1.f / se;
        t[0] = t[1] = t[2] = t[3] = 0.f;
        float cum = 0.f;
        for (int j = 0; j < 7; ++j) { cum += e[j] * inv; t[4 + j] = cum; }
        t[11] = t[12] = t[13] = 1.f;
        cc[0] = 0.f;
        for (int j = 0; j < 9; ++j) cc[1 + j] = wv[j];
    }
    __syncthreads();

    if (tid < 7) {
        // Symbolic de Boor for interval tid (knot span k = 3+tid), polynomial
        // in u = xq - t[k]. alpha = (xq - tlo)/(thi - tlo) = A + B*u;
        // every denominator spans >= 1 interior knot gap -> strictly > 0.
        const int k = 3 + tid;
        const float tk = t[k];
        float d[4][4];
        for (int j = 0; j < 4; ++j) {
            d[j][0] = cc[k - 3 + j];
            d[j][1] = d[j][2] = d[j][3] = 0.f;
        }
        for (int r = 1; r <= 3; ++r) {
            for (int j = 3; j >= r; --j) {
                const float tlo = t[k + j - 3];
                const float thi = t[k + j + 1 - r];
                const float B = 1.f / (thi - tlo);
                const float A = (tk - tlo) * B;
                float nd[4];
                for (int nn = 0; nn < 4; ++nn) nd[nn] = d[j - 1][nn];
                for (int nn = 0; nn < r; ++nn) {
                    const float en = d[j][nn] - d[j - 1][nn];
                    nd[nn]     += A * en;
                    nd[nn + 1] += B * en;
                }
                for (int nn = 0; nn < 4; ++nn) d[j][nn] = nd[nn];
            }
        }
        d3[tid] = d[3][3];
        if (tid == 0) {   // interval 0 has tk = 0 -> already expanded in x
            p0[0] = d[3][0]; p0[1] = d[3][1]; p0[2] = d[3][2]; p0[3] = d[3][3];
        }
    }
    __syncthreads();

    if (tid < 16) {
        float val;
        if (tid < 4)       val = p0[tid];
        else if (tid < 10) val = t[tid];               // t[4..9] == k1..k6
        else               val = d3[tid - 9] - d3[tid - 10];  // e_{tid-9}
        ws[tid] = val;
    }
}

// ---------------------------------------------------------------------------
// Kernel 2: streaming eval. All 16 params wave-uniform in registers.
// No LDS, no barriers, no lane-varying gathers: pure stream + VALU.
// ---------------------------------------------------------------------------
__device__ __forceinline__ float eval_one(float xv,
                                          float c0, float c1, float c2, float c3,
                                          float k1, float k2, float k3,
                                          float k4, float k5, float k6,
                                          float e1, float e2, float e3,
                                          float e4, float e5, float e6)
{
    const float xq = fminf(fmaxf(xv * 0.57735026918962576f, 0.0f), 0.9999f);
    float acc = fmaf(fmaf(fmaf(c3, xq, c2), xq, c1), xq, c0);
    float r;
    r = fmaxf(xq - k1, 0.f); acc = fmaf(e1 * r, r * r, acc);
    r = fmaxf(xq - k2, 0.f); acc = fmaf(e2 * r, r * r, acc);
    r = fmaxf(xq - k3, 0.f); acc = fmaf(e3 * r, r * r, acc);
    r = fmaxf(xq - k4, 0.f); acc = fmaf(e4 * r, r * r, acc);
    r = fmaxf(xq - k5, 0.f); acc = fmaf(e5 * r, r * r, acc);
    r = fmaxf(xq - k6, 0.f); acc = fmaf(e6 * r, r * r, acc);
    return acc;
}

__global__ __launch_bounds__(256) void nsf_eval_kernel(const float* __restrict__ x,
                                                       const float* __restrict__ ws,
                                                       float* __restrict__ out, int n)
{
    const float c0 = ws[0],  c1 = ws[1],  c2 = ws[2],  c3 = ws[3];
    const float k1 = ws[4],  k2 = ws[5],  k3 = ws[6],  k4 = ws[7],  k5 = ws[8],  k6 = ws[9];
    const float e1 = ws[10], e2 = ws[11], e3 = ws[12], e4 = ws[13], e5 = ws[14], e6 = ws[15];

    const int n4 = n >> 2;
    const int gid = blockIdx.x * blockDim.x + threadIdx.x;
    const int stride = gridDim.x * blockDim.x;

    const f4* __restrict__ x4 = reinterpret_cast<const f4*>(x);
    f4* __restrict__ o4 = reinterpret_cast<f4*>(out);

    for (int idx = gid; idx < n4; idx += stride) {
        const f4 v = x4[idx];
        f4 r;
        r.x = eval_one(v.x, c0,c1,c2,c3, k1,k2,k3,k4,k5,k6, e1,e2,e3,e4,e5,e6);
        r.y = eval_one(v.y, c0,c1,c2,c3, k1,k2,k3,k4,k5,k6, e1,e2,e3,e4,e5,e6);
        r.z = eval_one(v.z, c0,c1,c2,c3, k1,k2,k3,k4,k5,k6, e1,e2,e3,e4,e5,e6);
        r.w = eval_one(v.w, c0,c1,c2,c3, k1,k2,k3,k4,k5,k6, e1,e2,e3,e4,e5,e6);
        __builtin_nontemporal_store(r, o4 + idx);
    }
    // scalar tail (n % 4 != 0 safety; empty at n = 256^3)
    for (int j = (n4 << 2) + gid; j < n; j += stride)
        out[j] = eval_one(x[j], c0,c1,c2,c3, k1,k2,k3,k4,k5,k6, e1,e2,e3,e4,e5,e6);
}

extern "C" void kernel_launch(void* const* d_in, const int* in_sizes, int n_in,
                              void* d_out, int out_size, void* d_ws, size_t ws_size,
                              hipStream_t stream)
{
    const float* x  = (const float*)d_in[0];
    const float* a  = (const float*)d_in[1];
    const float* W1 = (const float*)d_in[2];
    const float* b1 = (const float*)d_in[3];
    const float* W2 = (const float*)d_in[4];
    const float* b2 = (const float*)d_in[5];
    const float* Ww = (const float*)d_in[6];
    const float* bw = (const float*)d_in[7];
    const float* Wk = (const float*)d_in[8];
    const float* bk = (const float*)d_in[9];
    float* out = (float*)d_out;
    float* ws  = (float*)d_ws;
    const int n = out_size;

    hipLaunchKernelGGL(nsf_params_kernel, dim3(1), dim3(64), 0, stream,
                       a, W1, b1, W2, b2, Ww, bw, Wk, bk, ws);

    // 2048 blocks x 256 = 8192 waves (32/CU): saturates HBM; 8 float4/thread.
    hipLaunchKernelGGL(nsf_eval_kernel, dim3(2048), dim3(256), 0, stream,
                       x, ws, out, n);
}